// Round 6
// baseline (400.444 us; speedup 1.0000x reference)
//
#include <hip/hip_runtime.h>
#include <hip/hip_cooperative_groups.h>
#include <math.h>

namespace cg = cooperative_groups;

#define H 128
#define HID 512
#define NB 1024            // cooperative grid: 1024 blocks x 256 (4 blocks/CU)
#define PREP_B 16

struct Ws {
    float sb_part[PREP_B];
    float u_part[PREP_B][H];
    unsigned long long best_part[NB];
    float Z_part[NB];
};

__device__ __forceinline__ unsigned int fkey(float f) {
    unsigned int u = __float_as_uint(f);
    return (u & 0x80000000u) ? ~u : (u | 0x80000000u);
}
__device__ __forceinline__ float inv_fkey(unsigned int k) {
    return __uint_as_float((k & 0x80000000u) ? (k ^ 0x80000000u) : ~k);
}

// one kernel: prep (16 blocks) -> grid.sync -> stream+score (all) -> grid.sync
// -> reduce (block 0). No contended atomics anywhere; partials via plain stores
// with grid.sync providing cross-XCD visibility.
__global__ __launch_bounds__(256, 4)
void fused_kernel(const float* __restrict__ outp, const float* __restrict__ adj,
                  const float* __restrict__ W1, const float* __restrict__ b1,
                  const float* __restrict__ W2, const float* __restrict__ b2,
                  const int* __restrict__ prev, Ws* __restrict__ ws,
                  float* __restrict__ out, int n, int ntiles) {
    __shared__ float phi1_s[32];
    __shared__ float sb_s[8];
    __shared__ float u_s[2][H];
    __shared__ float zs[4];
    __shared__ unsigned long long bs[4];
    cg::grid_group grid = cg::this_grid();

    int t = threadIdx.x;
    int lane = t & 63;
    int c = lane & 31;
    int hv = lane >> 5;
    int w = t >> 6;
    int blk = blockIdx.x;

    // ---------------- phase 1: prep on blocks 0..15 --------------------------
    if (blk < PREP_B) {
        int g = t >> 5;                  // half-wave 0..7, 4 rows each
        int kbase = blk * 32;
        const float4* vi = (const float4*)(outp + (size_t)prev[0] * H);
        float4 v = vi[c];
        float sb = 0.f;
#pragma unroll
        for (int r = 0; r < 4; ++r) {
            int kl = g * 4 + r;
            int k = kbase + kl;
            float4 wv = ((const float4*)(W1 + (size_t)k * H))[c];
            float d = wv.x * v.x + wv.y * v.y + wv.z * v.z + wv.w * v.w;
            d += __shfl_xor(d, 16);
            d += __shfl_xor(d, 8);
            d += __shfl_xor(d, 4);
            d += __shfl_xor(d, 2);
            d += __shfl_xor(d, 1);
            if (c == 0) {
                float phi = d + b1[k];
                phi1_s[kl] = phi;
                sb += phi * b2[k];
            }
        }
        if (c == 0) sb_s[g] = sb;
        __syncthreads();
        int h = t & 127;
        int g2 = t >> 7;                 // 0..1
        float up = 0.f;
#pragma unroll
        for (int kk = 0; kk < 16; ++kk) {
            int kl = g2 * 16 + kk;
            up += phi1_s[kl] * W2[(size_t)(kbase + kl) * H + h];
        }
        u_s[g2][h] = up;
        __syncthreads();
        if (t < H) ws->u_part[blk][t] = u_s[0][t] + u_s[1][t];
        if (t == 0) {
            float s = 0.f;
#pragma unroll
            for (int i = 0; i < 8; ++i) s += sb_s[i];
            ws->sb_part[blk] = s;
        }
    }

    grid.sync();

    // ---------------- phase 2: streaming score -------------------------------
    const float inv = 0.04419417382415922f;     // 1/sqrt(512)
    float4 uv = make_float4(0.f, 0.f, 0.f, 0.f);
    float s_b = 0.f;
#pragma unroll
    for (int b = 0; b < PREP_B; ++b) {
        float4 p = ((const float4*)ws->u_part[b])[c];
        uv.x += p.x; uv.y += p.y; uv.z += p.z; uv.w += p.w;
        s_b += ws->sb_part[b];
    }
    float zloc = 0.f;
    float bscore = -3.4e38f;
    int bidx = -1;
    const float4* xv = (const float4*)outp;
    for (int tile = blk; tile < ntiles; tile += NB) {
        int base = tile * 32 + w * 8 + hv;
        // tail lane's own adj value: issue FIRST, independent of x loads
        float aown = 0.f;
        int trow = base + 2 * c;                 // valid for c<4
        if (c < 4 && trow < n) aown = adj[trow];
        float4 x[4];
#pragma unroll
        for (int r = 0; r < 4; ++r) {
            int row = base + 2 * r;
            if (row >= n) row = n - 1;           // clamp (value unused OOB)
            x[r] = xv[(size_t)row * 32 + c];
        }
        float d[4];
#pragma unroll
        for (int r = 0; r < 4; ++r) {
            float dd = x[r].x * uv.x + x[r].y * uv.y + x[r].z * uv.z + x[r].w * uv.w;
            dd += __shfl_xor(dd, 16);
            dd += __shfl_xor(dd, 8);
            dd += __shfl_xor(dd, 4);
            dd += __shfl_xor(dd, 2);
            dd += __shfl_xor(dd, 1);
            d[r] = dd;
        }
        if (c < 4 && trow < n) {
            float dm = d[0];
#pragma unroll
            for (int r = 1; r < 4; ++r) dm = (c == r) ? d[r] : dm;
            if (aown != 0.f) {
                float score = (s_b + aown * dm) * inv;
                float e = __expf(2.f * score);   // fast tanh
                float attn = 10.f * ((e - 1.f) / (e + 1.f));
                zloc += __expf(attn);
                if (score > bscore) { bscore = score; bidx = trow; }
            } else {
                zloc += 1.0f;                    // exp(0)
            }
        }
    }
#pragma unroll
    for (int m = 32; m >= 1; m >>= 1) zloc += __shfl_xor(zloc, m);
    unsigned long long pk = 0ull;
    if (bidx >= 0)
        pk = ((unsigned long long)fkey(bscore) << 32) |
             (unsigned long long)(0xFFFFFFFFu - (unsigned int)bidx);
#pragma unroll
    for (int m = 32; m >= 1; m >>= 1) {
        unsigned long long o = __shfl_xor(pk, m);
        if (o > pk) pk = o;
    }
    __syncthreads();                             // reuse zs/bs safely
    if (lane == 0) { zs[w] = zloc; bs[w] = pk; }
    __syncthreads();
    if (t == 0) {
        float z = zs[0] + zs[1] + zs[2] + zs[3];
        unsigned long long p2 = bs[0];
#pragma unroll
        for (int i = 1; i < 4; ++i) if (bs[i] > p2) p2 = bs[i];
        ws->Z_part[blk] = z;
        ws->best_part[blk] = p2;
    }

    grid.sync();

    // ---------------- phase 3: reduce on block 0 -----------------------------
    if (blk == 0) {
        float z = 0.f;
        unsigned long long pk2 = 0ull;
#pragma unroll
        for (int i = 0; i < 4; ++i) {
            int s = t + 256 * i;
            z += ws->Z_part[s];
            unsigned long long o = ws->best_part[s];
            if (o > pk2) pk2 = o;
        }
#pragma unroll
        for (int m = 32; m >= 1; m >>= 1) {
            z += __shfl_xor(z, m);
            unsigned long long o = __shfl_xor(pk2, m);
            if (o > pk2) pk2 = o;
        }
        __syncthreads();
        if (lane == 0) { zs[w] = z; bs[w] = pk2; }
        __syncthreads();
        if (t == 0) {
            float Z = zs[0] + zs[1] + zs[2] + zs[3];
            unsigned long long b = bs[0];
#pragma unroll
            for (int i = 1; i < 4; ++i) if (bs[i] > b) b = bs[i];
            unsigned int idx = 0xFFFFFFFFu - (unsigned int)(b & 0xFFFFFFFFu);
            float score = inv_fkey((unsigned int)(b >> 32));
            float p = __expf(10.f * tanhf(score)) / Z;
            if (b == 0ull) { idx = 0; p = 0.f; }
            out[0] = (float)idx;
            out[1] = p;
        }
    }
}

extern "C" void kernel_launch(void* const* d_in, const int* in_sizes, int n_in,
                              void* d_out, int out_size, void* d_ws, size_t ws_size,
                              hipStream_t stream) {
    const float* outp = (const float*)d_in[0];
    const float* adj  = (const float*)d_in[1];
    const float* W1   = (const float*)d_in[2];
    const float* b1   = (const float*)d_in[3];
    const float* W2   = (const float*)d_in[4];
    const float* b2   = (const float*)d_in[5];
    const int*   prev = (const int*)d_in[6];
    int n = in_sizes[1];                       // N = 200000
    Ws* ws = (Ws*)d_ws;
    float* out = (float*)d_out;
    int ntiles = (n + 31) / 32;                // 6250

    void* args[] = { (void*)&outp, (void*)&adj, (void*)&W1, (void*)&b1,
                     (void*)&W2, (void*)&b2, (void*)&prev, (void*)&ws,
                     (void*)&out, (void*)&n, (void*)&ntiles };
    hipLaunchCooperativeKernel((const void*)fused_kernel, dim3(NB), dim3(256),
                               args, 0, stream);
}

// Round 7
// 214.037 us; speedup vs baseline: 1.8709x; 1.8709x over previous
//
#include <hip/hip_runtime.h>
#include <math.h>

#define H 128
#define HID 512
#define NB 1024            // main grid: 1024 blocks x 256 threads
#define PREP_B 32          // producer blocks (blockIdx 0..31), 16 phi1-rows each
#define MAGIC 0x5EED5EEDu

struct Ws {
    unsigned int flag[PREP_B];            // poison-safe handshake flags
    float sb_part[PREP_B];
    float u_part[PREP_B][H];
    unsigned long long best_part[NB];
    float Z_part[NB];
};

__device__ __forceinline__ unsigned int fkey(float f) {
    unsigned int u = __float_as_uint(f);
    return (u & 0x80000000u) ? ~u : (u | 0x80000000u);
}
__device__ __forceinline__ float inv_fkey(unsigned int k) {
    return __uint_as_float((k & 0x80000000u) ? (k ^ 0x80000000u) : ~k);
}

// ---------------- main: producer blocks 0..31 + streaming score ---------------
__global__ __launch_bounds__(256)
void main_kernel(const float* __restrict__ outp, const float* __restrict__ adj,
                 const float* __restrict__ W1, const float* __restrict__ b1,
                 const float* __restrict__ W2, const float* __restrict__ b2,
                 const int* __restrict__ prev, Ws* __restrict__ ws,
                 int n, int ntiles) {
    __shared__ float phi1_s[16];
    __shared__ float sb_s[8];
    __shared__ float u_s[2][H];
    __shared__ float zs[4];
    __shared__ unsigned long long bs[4];

    int t = threadIdx.x;
    int lane = t & 63;
    int c = lane & 31;
    int hv = lane >> 5;
    int w = t >> 6;
    int blk = blockIdx.x;

    // ---- phase 1: blocks 0..31 produce u_part[blk] (16 rows of phi1 each) ----
    if (blk < PREP_B) {
        int g = t >> 5;                  // half-wave 0..7, 2 rows each
        int kbase = blk * 16;
        const float4* vi = (const float4*)(outp + (size_t)prev[0] * H);
        float4 v = vi[c];
        float sb = 0.f;
#pragma unroll
        for (int r = 0; r < 2; ++r) {
            int kl = g * 2 + r;          // 0..15
            int k = kbase + kl;
            float4 wv = ((const float4*)(W1 + (size_t)k * H))[c];
            float d = wv.x * v.x + wv.y * v.y + wv.z * v.z + wv.w * v.w;
            d += __shfl_xor(d, 16);
            d += __shfl_xor(d, 8);
            d += __shfl_xor(d, 4);
            d += __shfl_xor(d, 2);
            d += __shfl_xor(d, 1);
            if (c == 0) {
                float phi = d + b1[k];
                phi1_s[kl] = phi;
                sb += phi * b2[k];
            }
        }
        if (c == 0) sb_s[g] = sb;
        __syncthreads();
        int h = t & 127;
        int g2 = t >> 7;                 // 0..1, 8 k's each
        float up = 0.f;
#pragma unroll
        for (int kk = 0; kk < 8; ++kk) {
            int kl = g2 * 8 + kk;
            up += phi1_s[kl] * W2[(size_t)(kbase + kl) * H + h];
        }
        u_s[g2][h] = up;
        __syncthreads();
        if (t < H)
            __hip_atomic_store(&ws->u_part[blk][t], u_s[0][t] + u_s[1][t],
                               __ATOMIC_RELAXED, __HIP_MEMORY_SCOPE_AGENT);
        if (t == 0) {
            float s = 0.f;
#pragma unroll
            for (int i = 0; i < 8; ++i) s += sb_s[i];
            __hip_atomic_store(&ws->sb_part[blk], s,
                               __ATOMIC_RELAXED, __HIP_MEMORY_SCOPE_AGENT);
            __threadfence();
            __hip_atomic_store(&ws->flag[blk], MAGIC,
                               __ATOMIC_RELEASE, __HIP_MEMORY_SCOPE_AGENT);
        }
    }

    // ---- handshake: wave 0 polls the 32 flags (read-only, throttled) ---------
    if (t < 64) {
        for (;;) {
            int ok = 1;
            if (t < PREP_B)
                ok = (__hip_atomic_load(&ws->flag[t], __ATOMIC_ACQUIRE,
                                        __HIP_MEMORY_SCOPE_AGENT) == MAGIC);
            unsigned long long vote = __ballot(ok != 0);
            if (vote == ~0ull) break;
            __builtin_amdgcn_s_sleep(16);
        }
    }
    __syncthreads();

    // ---- fold the 32 u/sb partials (L2/LLC-hot, ~16.5 KB) --------------------
    const float inv = 0.04419417382415922f;     // 1/sqrt(512)
    float4 uv = make_float4(0.f, 0.f, 0.f, 0.f);
    float s_b = 0.f;
#pragma unroll
    for (int b = 0; b < PREP_B; ++b) {
        float4 p = ((const float4*)ws->u_part[b])[c];
        uv.x += p.x; uv.y += p.y; uv.z += p.z; uv.w += p.w;
        s_b += ws->sb_part[b];
    }

    // ---- phase 2: streaming score (R4-proven structure) ----------------------
    float zloc = 0.f;
    float bscore = -3.4e38f;
    int bidx = -1;
    const float4* xv = (const float4*)outp;
    for (int tile = blk; tile < ntiles; tile += NB) {
        int base = tile * 32 + w * 8 + hv;
        float aown = 0.f;
        int trow = base + 2 * c;                 // valid for c<4
        if (c < 4 && trow < n) aown = adj[trow];
        float4 x[4];
#pragma unroll
        for (int r = 0; r < 4; ++r) {
            int row = base + 2 * r;
            if (row >= n) row = n - 1;           // clamp (value unused OOB)
            x[r] = xv[(size_t)row * 32 + c];
        }
        float d[4];
#pragma unroll
        for (int r = 0; r < 4; ++r) {
            float dd = x[r].x * uv.x + x[r].y * uv.y + x[r].z * uv.z + x[r].w * uv.w;
            dd += __shfl_xor(dd, 16);
            dd += __shfl_xor(dd, 8);
            dd += __shfl_xor(dd, 4);
            dd += __shfl_xor(dd, 2);
            dd += __shfl_xor(dd, 1);
            d[r] = dd;
        }
        if (c < 4 && trow < n) {
            float dm = d[0];
#pragma unroll
            for (int r = 1; r < 4; ++r) dm = (c == r) ? d[r] : dm;
            if (aown != 0.f) {
                float score = (s_b + aown * dm) * inv;
                float e = __expf(2.f * score);   // fast tanh
                float attn = 10.f * ((e - 1.f) / (e + 1.f));
                zloc += __expf(attn);
                if (score > bscore) { bscore = score; bidx = trow; }
            } else {
                zloc += 1.0f;                    // exp(0)
            }
        }
    }
#pragma unroll
    for (int m = 32; m >= 1; m >>= 1) zloc += __shfl_xor(zloc, m);
    unsigned long long pk = 0ull;
    if (bidx >= 0)
        pk = ((unsigned long long)fkey(bscore) << 32) |
             (unsigned long long)(0xFFFFFFFFu - (unsigned int)bidx);
#pragma unroll
    for (int m = 32; m >= 1; m >>= 1) {
        unsigned long long o = __shfl_xor(pk, m);
        if (o > pk) pk = o;
    }
    if (lane == 0) { zs[w] = zloc; bs[w] = pk; }
    __syncthreads();
    if (t == 0) {
        float z = zs[0] + zs[1] + zs[2] + zs[3];
        unsigned long long p2 = bs[0];
#pragma unroll
        for (int i = 1; i < 4; ++i) if (bs[i] > p2) p2 = bs[i];
        ws->Z_part[blk] = z;                   // plain stores, own slot
        ws->best_part[blk] = p2;
    }
}

// ---------------- reduce: 1 block, 1024 threads -------------------------------
__global__ __launch_bounds__(1024)
void reduce_kernel(const Ws* __restrict__ ws, float* __restrict__ outp) {
    __shared__ float zs[16];
    __shared__ unsigned long long bs[16];
    int t = threadIdx.x;
    int lane = t & 63;
    float z = ws->Z_part[t];
    unsigned long long pk = ws->best_part[t];
#pragma unroll
    for (int m = 32; m >= 1; m >>= 1) {
        z += __shfl_xor(z, m);
        unsigned long long o = __shfl_xor(pk, m);
        if (o > pk) pk = o;
    }
    if (lane == 0) { zs[t >> 6] = z; bs[t >> 6] = pk; }
    __syncthreads();
    if (t == 0) {
        float Z = 0.f;
        unsigned long long b = 0ull;
#pragma unroll
        for (int i = 0; i < 16; ++i) { Z += zs[i]; if (bs[i] > b) b = bs[i]; }
        unsigned int idx = 0xFFFFFFFFu - (unsigned int)(b & 0xFFFFFFFFu);
        float score = inv_fkey((unsigned int)(b >> 32));
        float p = __expf(10.f * tanhf(score)) / Z;
        if (b == 0ull) { idx = 0; p = 0.f; }
        outp[0] = (float)idx;
        outp[1] = p;
    }
}

extern "C" void kernel_launch(void* const* d_in, const int* in_sizes, int n_in,
                              void* d_out, int out_size, void* d_ws, size_t ws_size,
                              hipStream_t stream) {
    const float* outp = (const float*)d_in[0];
    const float* adj  = (const float*)d_in[1];
    const float* W1   = (const float*)d_in[2];
    const float* b1   = (const float*)d_in[3];
    const float* W2   = (const float*)d_in[4];
    const float* b2   = (const float*)d_in[5];
    const int*   prev = (const int*)d_in[6];
    int n = in_sizes[1];                       // N = 200000
    Ws* ws = (Ws*)d_ws;
    int ntiles = (n + 31) / 32;                // 6250

    main_kernel<<<NB, 256, 0, stream>>>(outp, adj, W1, b1, W2, b2, prev, ws,
                                        n, ntiles);
    reduce_kernel<<<1, 1024, 0, stream>>>(ws, (float*)d_out);
}

// Round 8
// 169.299 us; speedup vs baseline: 2.3653x; 1.2643x over previous
//
#include <hip/hip_runtime.h>
#include <math.h>

#define H 128
#define HID 512
#define GRID 1024          // score blocks == partial slots
#define PREP_B 16          // prep blocks == u partial slots

struct Ws {
    float sb_part[PREP_B];
    float u_part[PREP_B][H];
    unsigned long long best_part[GRID];   // 8-aligned
    float Z_part[GRID];
};

__device__ __forceinline__ unsigned int fkey(float f) {
    unsigned int u = __float_as_uint(f);
    return (u & 0x80000000u) ? ~u : (u | 0x80000000u);
}
__device__ __forceinline__ float inv_fkey(unsigned int k) {
    return __uint_as_float((k & 0x80000000u) ? (k ^ 0x80000000u) : ~k);
}

// ---------------- prep: 16 independent blocks (R4-proven, ~4 us) --------------
__global__ __launch_bounds__(256)
void prep_kernel(const float* __restrict__ outp, const float* __restrict__ W1,
                 const float* __restrict__ b1, const float* __restrict__ W2,
                 const float* __restrict__ b2, const int* __restrict__ prev,
                 Ws* __restrict__ ws) {
    __shared__ float phi1_s[32];
    __shared__ float sb_s[8];
    __shared__ float u_s[2][H];
    int t = threadIdx.x;
    int lane = t & 63;
    int c = lane & 31;
    int g = t >> 5;            // half-wave id 0..7, each owns 4 rows
    int kbase = blockIdx.x * 32;
    const float4* vi = (const float4*)(outp + (size_t)prev[0] * H);
    float4 v = vi[c];
    float sb = 0.f;
#pragma unroll
    for (int r = 0; r < 4; ++r) {
        int kl = g * 4 + r;
        int k = kbase + kl;
        float4 w = ((const float4*)(W1 + (size_t)k * H))[c];
        float d = w.x * v.x + w.y * v.y + w.z * v.z + w.w * v.w;
        d += __shfl_xor(d, 16);
        d += __shfl_xor(d, 8);
        d += __shfl_xor(d, 4);
        d += __shfl_xor(d, 2);
        d += __shfl_xor(d, 1);
        if (c == 0) {
            float phi = d + b1[k];
            phi1_s[kl] = phi;
            sb += phi * b2[k];
        }
    }
    if (c == 0) sb_s[g] = sb;
    __syncthreads();
    int h = t & 127;
    int g2 = t >> 7;           // 0..1
    float up = 0.f;
#pragma unroll
    for (int kk = 0; kk < 16; ++kk) {
        int kl = g2 * 16 + kk;
        up += phi1_s[kl] * W2[(size_t)(kbase + kl) * H + h];
    }
    u_s[g2][h] = up;
    __syncthreads();
    if (t < H) ws->u_part[blockIdx.x][t] = u_s[0][t] + u_s[1][t];
    if (t == 0) {
        float s = 0.f;
#pragma unroll
        for (int i = 0; i < 8; ++i) s += sb_s[i];
        ws->sb_part[blockIdx.x] = s;
    }
}

// ---------------- main streaming pass: ILP-8, no clamps, no gating ------------
// Tile = 64 rows/block-iter (N = 3125*64 exactly -> no bounds checks in loop).
// Wave w owns rows tile*64 + w*16 .. +15; half-wave handles 8 rows
// (row = base + 2r), 32 float4 loads in flight per half-wave-iter.
__global__ __launch_bounds__(256)
void score_kernel(const float4* __restrict__ xv, const float* __restrict__ adj,
                  Ws* __restrict__ ws, int n, int ntiles) {
    __shared__ float zs[4];
    __shared__ unsigned long long bs[4];
    const float inv = 0.04419417382415922f;   // 1/sqrt(512)
    int t = threadIdx.x;
    int lane = t & 63;
    int c = lane & 31;
    int hv = lane >> 5;
    int w = t >> 6;
    // fold the 16 u/sb partials (8 KB, L2/LLC-hot)
    float4 uv = make_float4(0.f, 0.f, 0.f, 0.f);
    float s_b = 0.f;
#pragma unroll
    for (int b = 0; b < PREP_B; ++b) {
        float4 p = ((const float4*)ws->u_part[b])[c];
        uv.x += p.x; uv.y += p.y; uv.z += p.z; uv.w += p.w;
        s_b += ws->sb_part[b];
    }
    float zloc = 0.f;
    float bscore = -3.4e38f;
    int bidx = -1;

    // ---- generic remainder (n % 64 rows), block 0 only; dormant at N=200000 --
    int nfull = ntiles * 64;
    if (blockIdx.x == 0 && nfull < n) {
        for (int row = nfull + (t >> 5); row < n; row += 8) {
            float4 x = xv[(size_t)row * 32 + c];
            float dd = x.x * uv.x + x.y * uv.y + x.z * uv.z + x.w * uv.w;
            dd += __shfl_xor(dd, 16);
            dd += __shfl_xor(dd, 8);
            dd += __shfl_xor(dd, 4);
            dd += __shfl_xor(dd, 2);
            dd += __shfl_xor(dd, 1);
            if (c == 0) {
                float a = adj[row];
                if (a != 0.f) {
                    float score = (s_b + a * dd) * inv;
                    float e = __expf(2.f * score);
                    float attn = 10.f * ((e - 1.f) / (e + 1.f));
                    zloc += __expf(attn);
                    if (score > bscore) { bscore = score; bidx = row; }
                } else zloc += 1.0f;
            }
        }
    }

    // ---- main loop: ~3 iterations of 64 rows --------------------------------
    for (int tile = blockIdx.x; tile < ntiles; tile += GRID) {
        int base = tile * 64 + w * 16 + hv;
        // own-adj load issues first, independent of everything
        float aown = 0.f;
        int trow = base + 2 * c;                  // meaningful for c<8
        if (c < 8) aown = adj[trow];
        float4 x[8];
#pragma unroll
        for (int r = 0; r < 8; ++r)
            x[r] = xv[(size_t)(base + 2 * r) * 32 + c];
        float d[8];
#pragma unroll
        for (int r = 0; r < 8; ++r) {
            float dd = x[r].x * uv.x + x[r].y * uv.y + x[r].z * uv.z + x[r].w * uv.w;
            dd += __shfl_xor(dd, 16);
            dd += __shfl_xor(dd, 8);
            dd += __shfl_xor(dd, 4);
            dd += __shfl_xor(dd, 2);
            dd += __shfl_xor(dd, 1);
            d[r] = dd;                            // full dot in all 32 lanes
        }
        if (c < 8) {
            float dm = d[0];
#pragma unroll
            for (int r = 1; r < 8; ++r) dm = (c == r) ? d[r] : dm;
            if (aown != 0.f) {
                float score = (s_b + aown * dm) * inv;
                float e = __expf(2.f * score);    // fast tanh
                float attn = 10.f * ((e - 1.f) / (e + 1.f));
                zloc += __expf(attn);
                if (score > bscore) { bscore = score; bidx = trow; }
            } else {
                zloc += 1.0f;                     // exp(0)
            }
        }
    }
    // wave-wide reduce
#pragma unroll
    for (int m = 32; m >= 1; m >>= 1) zloc += __shfl_xor(zloc, m);
    unsigned long long pk = 0ull;
    if (bidx >= 0)
        pk = ((unsigned long long)fkey(bscore) << 32) |
             (unsigned long long)(0xFFFFFFFFu - (unsigned int)bidx);
#pragma unroll
    for (int m = 32; m >= 1; m >>= 1) {
        unsigned long long o = __shfl_xor(pk, m);
        if (o > pk) pk = o;
    }
    if (lane == 0) { zs[w] = zloc; bs[w] = pk; }
    __syncthreads();
    if (t == 0) {
        float z = zs[0] + zs[1] + zs[2] + zs[3];
        unsigned long long p2 = bs[0];
#pragma unroll
        for (int i = 1; i < 4; ++i) if (bs[i] > p2) p2 = bs[i];
        ws->Z_part[blockIdx.x] = z;            // plain stores, own slot
        ws->best_part[blockIdx.x] = p2;
    }
}

// ---------------- reduce: 1 block, 1024 threads -------------------------------
__global__ __launch_bounds__(1024)
void reduce_kernel(const Ws* __restrict__ ws, float* __restrict__ outp) {
    __shared__ float zs[16];
    __shared__ unsigned long long bs[16];
    int t = threadIdx.x;
    int lane = t & 63;
    float z = ws->Z_part[t];
    unsigned long long pk = ws->best_part[t];
#pragma unroll
    for (int m = 32; m >= 1; m >>= 1) {
        z += __shfl_xor(z, m);
        unsigned long long o = __shfl_xor(pk, m);
        if (o > pk) pk = o;
    }
    if (lane == 0) { zs[t >> 6] = z; bs[t >> 6] = pk; }
    __syncthreads();
    if (t == 0) {
        float Z = 0.f;
        unsigned long long b = 0ull;
#pragma unroll
        for (int i = 0; i < 16; ++i) { Z += zs[i]; if (bs[i] > b) b = bs[i]; }
        unsigned int idx = 0xFFFFFFFFu - (unsigned int)(b & 0xFFFFFFFFu);
        float score = inv_fkey((unsigned int)(b >> 32));
        float p = __expf(10.f * tanhf(score)) / Z;
        if (b == 0ull) { idx = 0; p = 0.f; }
        outp[0] = (float)idx;
        outp[1] = p;
    }
}

extern "C" void kernel_launch(void* const* d_in, const int* in_sizes, int n_in,
                              void* d_out, int out_size, void* d_ws, size_t ws_size,
                              hipStream_t stream) {
    const float* outp = (const float*)d_in[0];
    const float* adj  = (const float*)d_in[1];
    const float* W1   = (const float*)d_in[2];
    const float* b1   = (const float*)d_in[3];
    const float* W2   = (const float*)d_in[4];
    const float* b2   = (const float*)d_in[5];
    const int*   prev = (const int*)d_in[6];
    int n = in_sizes[1];                       // N = 200000
    Ws* ws = (Ws*)d_ws;
    int ntiles = n >> 6;                       // 3125 full 64-row tiles

    prep_kernel<<<PREP_B, 256, 0, stream>>>(outp, W1, b1, W2, b2, prev, ws);
    score_kernel<<<GRID, 256, 0, stream>>>((const float4*)outp, adj, ws, n, ntiles);
    reduce_kernel<<<1, 1024, 0, stream>>>(ws, (float*)d_out);
}